// Round 1
// baseline (251.028 us; speedup 1.0000x reference)
//
#include <hip/hip_runtime.h>
#include <cstdint>

#define B_ 2
#define S_ 2048
#define D_ 1024
#define H_ 16
#define DK_ 64

typedef float f32x4 __attribute__((ext_vector_type(4)));
typedef __bf16 bf16x8 __attribute__((ext_vector_type(8)));
typedef unsigned short u16x8 __attribute__((ext_vector_type(8)));
typedef unsigned short u16x4 __attribute__((ext_vector_type(4)));

__device__ __forceinline__ unsigned short f2bf(float x) {
  unsigned int u = __builtin_bit_cast(unsigned int, x);
  u += 0x7FFFu + ((u >> 16) & 1u);   // round-to-nearest-even
  return (unsigned short)(u >> 16);
}

__device__ __forceinline__ void gload16(const void* g, void* l) {
  __builtin_amdgcn_global_load_lds((__attribute__((address_space(1))) void*)(void*)g,
                                   (__attribute__((address_space(3))) void*)l, 16, 0, 0);
}

// ---------------- fp32 -> bf16 convert (vectorized) ----------------
__global__ __launch_bounds__(256) void cvt_bf16_kernel(const float* __restrict__ in,
                                                       unsigned short* __restrict__ out, int n) {
  int idx = blockIdx.x * blockDim.x + threadIdx.x;
  int stride = gridDim.x * blockDim.x;
  for (int i = idx * 4; i < n; i += stride * 4) {
    f32x4 v = *(const f32x4*)(in + i);
    u16x4 o;
#pragma unroll
    for (int j = 0; j < 4; ++j) o[j] = f2bf(v[j]);
    *(u16x4*)(out + i) = o;
  }
}

// ---------------- weight transpose + convert: WT[n][k] = W[k][n] ----------------
__global__ __launch_bounds__(256) void wtrans_kernel(const float* __restrict__ w0, const float* __restrict__ w1,
                                                     const float* __restrict__ w2, const float* __restrict__ w3,
                                                     unsigned short* o0, unsigned short* o1,
                                                     unsigned short* o2, unsigned short* o3) {
  const float* W;
  unsigned short* O;
  if (blockIdx.z == 0) { W = w0; O = o0; }
  else if (blockIdx.z == 1) { W = w1; O = o1; }
  else if (blockIdx.z == 2) { W = w2; O = o2; }
  else { W = w3; O = o3; }
  __shared__ float t[32][33];
  int n0 = blockIdx.x * 32, k0 = blockIdx.y * 32;
  int tx = threadIdx.x, ty = threadIdx.y;  // block (32,8)
  for (int i = ty; i < 32; i += 8) t[i][tx] = W[(size_t)(k0 + i) * D_ + n0 + tx];
  __syncthreads();
  for (int i = ty; i < 32; i += 8) O[(size_t)(n0 + i) * D_ + k0 + tx] = f2bf(t[tx][i]);
}

// ---------------- 128x128 bf16 GEMM, B transposed (BT[n][k]), bias add ----------------
// C[m][n] = sum_k A[m][k]*BT[n][k] + bias[n]
template <bool OUT_F32>
__device__ __forceinline__ void gemm128(const unsigned short* __restrict__ A,
                                        const unsigned short* __restrict__ BT,
                                        const float* __restrict__ bias,
                                        void* __restrict__ Cp, int M, int N, int K) {
  __shared__ unsigned short Al[128 * 32];
  __shared__ unsigned short Bl[128 * 32];
  const int tid = threadIdx.x;
  const int lane = tid & 63;
  const int w = tid >> 6;
  const int wr = w >> 1, wc = w & 1;
  const int m0 = blockIdx.y * 128, n0 = blockIdx.x * 128;

  f32x4 acc[4][4] = {};
  const int nk = K / 32;
  const int srow = lane >> 2;        // 0..15 within 16-row chunk
  const int scol = (lane & 3) * 8;   // ushort offset within 32-col row

  const int fr = lane & 15;
  const int fc = (lane >> 4) * 8;

  for (int kt = 0; kt < nk; ++kt) {
    __syncthreads();
#pragma unroll
    for (int it = 0; it < 2; ++it) {
      int chunk = it * 4 + w;
      const unsigned short* ga = A + (size_t)(m0 + chunk * 16 + srow) * K + kt * 32 + scol;
      gload16(ga, &Al[chunk * 512]);
      const unsigned short* gb = BT + (size_t)(n0 + chunk * 16 + srow) * K + kt * 32 + scol;
      gload16(gb, &Bl[chunk * 512]);
    }
    __syncthreads();
    bf16x8 af[4], bf[4];
#pragma unroll
    for (int i = 0; i < 4; ++i)
      af[i] = __builtin_bit_cast(bf16x8, *(const u16x8*)&Al[(wr * 64 + i * 16 + fr) * 32 + fc]);
#pragma unroll
    for (int j = 0; j < 4; ++j)
      bf[j] = __builtin_bit_cast(bf16x8, *(const u16x8*)&Bl[(wc * 64 + j * 16 + fr) * 32 + fc]);
#pragma unroll
    for (int i = 0; i < 4; ++i)
#pragma unroll
      for (int j = 0; j < 4; ++j)
        acc[i][j] = __builtin_amdgcn_mfma_f32_16x16x32_bf16(af[i], bf[j], acc[i][j], 0, 0, 0);
  }

  const int rg = (lane >> 4) * 4;
  const int cg = lane & 15;
#pragma unroll
  for (int i = 0; i < 4; ++i)
#pragma unroll
    for (int j = 0; j < 4; ++j) {
      int col = n0 + wc * 64 + j * 16 + cg;
      float bv = bias[col];
#pragma unroll
      for (int e = 0; e < 4; ++e) {
        int row = m0 + wr * 64 + i * 16 + rg + e;
        float v = acc[i][j][e] + bv;
        if (OUT_F32)
          ((float*)Cp)[(size_t)row * N + col] = v;
        else
          ((unsigned short*)Cp)[(size_t)row * N + col] = f2bf(v);
      }
    }
}

__global__ __launch_bounds__(256) void qkv_gemm_kernel(
    const unsigned short* __restrict__ xq, const unsigned short* __restrict__ xk,
    const unsigned short* __restrict__ xv, const unsigned short* __restrict__ wtq,
    const unsigned short* __restrict__ wtk, const unsigned short* __restrict__ wtv,
    const float* __restrict__ bq, const float* __restrict__ bk, const float* __restrict__ bv,
    unsigned short* q, unsigned short* k, unsigned short* v) {
  const unsigned short *A, *BT;
  const float* bias;
  unsigned short* C;
  if (blockIdx.z == 0) { A = xq; BT = wtq; bias = bq; C = q; }
  else if (blockIdx.z == 1) { A = xk; BT = wtk; bias = bk; C = k; }
  else { A = xv; BT = wtv; bias = bv; C = v; }
  gemm128<false>(A, BT, bias, (void*)C, B_ * S_, D_, D_);
}

__global__ __launch_bounds__(256) void out_gemm_kernel(const unsigned short* __restrict__ x,
                                                       const unsigned short* __restrict__ wto,
                                                       const float* __restrict__ bo,
                                                       float* __restrict__ out) {
  gemm128<true>(x, wto, bo, (void*)out, B_ * S_, D_, D_);
}

// ---------------- flash attention ----------------
// Q,K,V bf16 [B,S,D] head-interleaved (head h = cols h*64..h*64+63). X out same layout.
__global__ __launch_bounds__(256) void attn_kernel(const unsigned short* __restrict__ Q,
                                                   const unsigned short* __restrict__ K,
                                                   const unsigned short* __restrict__ V,
                                                   const int* __restrict__ mask,
                                                   unsigned short* __restrict__ X) {
  __shared__ unsigned short Kl[64 * 64];   // [kr][d] bf16, XOR-swizzled rows
  __shared__ unsigned short Vt[64 * 72];   // V^T: [d][kr], padded to 72
  __shared__ unsigned short Pl[4][16 * 64];  // per-wave P tile, XOR-swizzled

  const int tid = threadIdx.x;
  const int lane = tid & 63;
  const int w = tid >> 6;
  const int qt = blockIdx.x;
  const int bh = blockIdx.y;
  const int b = bh >> 4, h = bh & 15;

  const size_t base = ((size_t)b * S_) * D_ + h * DK_;
  const int q0 = qt * 64 + w * 16;

  const int fr = lane & 15;
  const int fc = (lane >> 4) * 8;
  const int drow = (lane >> 4) * 4;
  const int dcol = lane & 15;

  // Q fragments (k-chunks 0..31, 32..63)
  bf16x8 qf[2];
  {
    const unsigned short* qp = Q + base + (size_t)(q0 + fr) * D_;
    qf[0] = __builtin_bit_cast(bf16x8, *(const u16x8*)(qp + fc));
    qf[1] = __builtin_bit_cast(bf16x8, *(const u16x8*)(qp + 32 + fc));
  }

  f32x4 acc[4] = {};
  float mst[4], lst[4];
#pragma unroll
  for (int e = 0; e < 4; ++e) { mst[e] = -1e30f; lst[e] = 0.f; }

  const int srow = tid >> 3;  // 0..31
  const int sseg = tid & 7;

  for (int kt = 0; kt < S_ / 64; ++kt) {
    __syncthreads();
    // stage K (swizzled) and V^T
#pragma unroll
    for (int p = 0; p < 2; ++p) {
      int r = srow + p * 32;
      const unsigned short* kp = K + base + (size_t)(kt * 64 + r) * D_ + sseg * 8;
      u16x8 kv = *(const u16x8*)kp;
      int koff = ((r * 128 + sseg * 16) ^ ((r & 7) << 4)) >> 1;
      *(u16x8*)&Kl[koff] = kv;
      const unsigned short* vp = V + base + (size_t)(kt * 64 + r) * D_ + sseg * 8;
      u16x8 vv = *(const u16x8*)vp;
#pragma unroll
      for (int j = 0; j < 8; ++j) Vt[(sseg * 8 + j) * 72 + r] = vv[j];
    }
    __syncthreads();

    // scores: 4 key col-tiles of 16
    f32x4 sc[4];
#pragma unroll
    for (int kc = 0; kc < 4; ++kc) {
      int krow = kc * 16 + fr;
      int kb0 = (krow * 128 + fc * 2) ^ ((krow & 7) << 4);
      int kb1 = (krow * 128 + 64 + fc * 2) ^ ((krow & 7) << 4);
      bf16x8 k0 = __builtin_bit_cast(bf16x8, *(const u16x8*)&Kl[kb0 >> 1]);
      bf16x8 k1 = __builtin_bit_cast(bf16x8, *(const u16x8*)&Kl[kb1 >> 1]);
      f32x4 s = {};
      s = __builtin_amdgcn_mfma_f32_16x16x32_bf16(qf[0], k0, s, 0, 0, 0);
      s = __builtin_amdgcn_mfma_f32_16x16x32_bf16(qf[1], k1, s, 0, 0, 0);
      const int kcol_g = kt * 64 + kc * 16 + dcol;
#pragma unroll
      for (int e = 0; e < 4; ++e) {
        int qrow_g = qt * 64 + w * 16 + drow + e;
        int mv = mask[((size_t)b * S_ + qrow_g) * S_ + kcol_g];
        s[e] = mv ? s[e] * 0.125f : -1e9f;
      }
      sc[kc] = s;
    }

    // online softmax (row stats across 16 lanes of each group)
    float alpha[4];
#pragma unroll
    for (int e = 0; e < 4; ++e) {
      float rm = fmaxf(fmaxf(sc[0][e], sc[1][e]), fmaxf(sc[2][e], sc[3][e]));
      rm = fmaxf(rm, __shfl_xor(rm, 1));
      rm = fmaxf(rm, __shfl_xor(rm, 2));
      rm = fmaxf(rm, __shfl_xor(rm, 4));
      rm = fmaxf(rm, __shfl_xor(rm, 8));
      float nm = fmaxf(mst[e], rm);
      alpha[e] = __expf(mst[e] - nm);
      mst[e] = nm;
      float rs = 0.f;
#pragma unroll
      for (int kc = 0; kc < 4; ++kc) {
        float p = __expf(sc[kc][e] - nm);
        sc[kc][e] = p;
        rs += p;
      }
      rs += __shfl_xor(rs, 1);
      rs += __shfl_xor(rs, 2);
      rs += __shfl_xor(rs, 4);
      rs += __shfl_xor(rs, 8);
      lst[e] = lst[e] * alpha[e] + rs;
#pragma unroll
      for (int nt = 0; nt < 4; ++nt) acc[nt][e] *= alpha[e];
    }

    // P -> bf16 -> per-wave LDS (swizzled). Same-wave producer/consumer: DS ops in-order.
    unsigned short* pw = &Pl[w][0];
#pragma unroll
    for (int kc = 0; kc < 4; ++kc)
#pragma unroll
      for (int e = 0; e < 4; ++e) {
        int row = drow + e, col = kc * 16 + dcol;
        int boff = (row * 128 + col * 2) ^ ((row & 7) << 4);
        pw[boff >> 1] = f2bf(sc[kc][e]);
      }

    // PV
#pragma unroll
    for (int c = 0; c < 2; ++c) {
      int pb = (fr * 128 + c * 64 + fc * 2) ^ ((fr & 7) << 4);
      bf16x8 pf = __builtin_bit_cast(bf16x8, *(const u16x8*)&pw[pb >> 1]);
#pragma unroll
      for (int nt = 0; nt < 4; ++nt) {
        bf16x8 vf = __builtin_bit_cast(bf16x8, *(const u16x8*)&Vt[(nt * 16 + fr) * 72 + c * 32 + fc]);
        acc[nt] = __builtin_amdgcn_mfma_f32_16x16x32_bf16(pf, vf, acc[nt], 0, 0, 0);
      }
    }
  }

  // epilogue: normalize and store
#pragma unroll
  for (int nt = 0; nt < 4; ++nt)
#pragma unroll
    for (int e = 0; e < 4; ++e) {
      int qrow_g = qt * 64 + w * 16 + drow + e;
      int col = h * DK_ + nt * 16 + dcol;
      X[((size_t)b * S_ + qrow_g) * D_ + col] = f2bf(acc[nt][e] / lst[e]);
    }
}

extern "C" void kernel_launch(void* const* d_in, const int* in_sizes, int n_in,
                              void* d_out, int out_size, void* d_ws, size_t ws_size,
                              hipStream_t stream) {
  const float* query = (const float*)d_in[0];
  const float* key = (const float*)d_in[1];
  const float* value = (const float*)d_in[2];
  const int* mask = (const int*)d_in[3];
  const float* Wq = (const float*)d_in[4];
  const float* bq = (const float*)d_in[5];
  const float* Wk = (const float*)d_in[6];
  const float* bk = (const float*)d_in[7];
  const float* Wv = (const float*)d_in[8];
  const float* bv = (const float*)d_in[9];
  const float* Wo = (const float*)d_in[10];
  const float* bo = (const float*)d_in[11];
  float* out = (float*)d_out;

  const size_t ACT = (size_t)B_ * S_ * D_;  // 4,194,304
  unsigned short* ws = (unsigned short*)d_ws;
  unsigned short* xq = ws;
  unsigned short* xk = xq + ACT;
  unsigned short* xv = xk + ACT;
  unsigned short* wtq = xv + ACT;
  unsigned short* wtk = wtq + (size_t)D_ * D_;
  unsigned short* wtv = wtk + (size_t)D_ * D_;
  unsigned short* wto = wtv + (size_t)D_ * D_;
  unsigned short* qb = wto + (size_t)D_ * D_;
  unsigned short* kb = qb + ACT;
  unsigned short* vb = kb + ACT;
  unsigned short* xb = vb + ACT;

  cvt_bf16_kernel<<<2048, 256, 0, stream>>>(query, xq, (int)ACT);
  cvt_bf16_kernel<<<2048, 256, 0, stream>>>(key, xk, (int)ACT);
  cvt_bf16_kernel<<<2048, 256, 0, stream>>>(value, xv, (int)ACT);

  dim3 tb(32, 8), tg(D_ / 32, D_ / 32, 4);
  wtrans_kernel<<<tg, tb, 0, stream>>>(Wq, Wk, Wv, Wo, wtq, wtk, wtv, wto);

  dim3 gg(D_ / 128, (B_ * S_) / 128, 3);
  qkv_gemm_kernel<<<gg, 256, 0, stream>>>(xq, xk, xv, wtq, wtk, wtv, bq, bk, bv, qb, kb, vb);

  dim3 ag(S_ / 64, B_ * H_);
  attn_kernel<<<ag, 256, 0, stream>>>(qb, kb, vb, mask, xb);

  dim3 og(D_ / 128, (B_ * S_) / 128, 1);
  out_gemm_kernel<<<og, 256, 0, stream>>>(xb, wto, bo, out);
}